// Round 4
// baseline (1998.202 us; speedup 1.0000x reference)
//
#include <hip/hip_runtime.h>
#include <hip/hip_bf16.h>

// SlicedLMHead: logits[2048][32000] = H[2048][4096] @ W[32000][4096]^T + bias
// Round 4: cvt W,H -> bf16 in d_ws, then 256x256 GEMM with software-pipelined
// LDS reads: 2 halves/K-tile, ONE barrier/tile, counted lgkmcnt(12) so
// ds_read_b128 of half h+1 executes UNDER the 32-MFMA cluster of half h.
// Staging: global_load_lds(16B), pre-swizzled source, vmcnt-before-barrier.

typedef __attribute__((ext_vector_type(8))) short bhalf8;   // 8 bf16
typedef __attribute__((ext_vector_type(4))) float f32x4;    // MFMA acc
typedef __attribute__((ext_vector_type(8))) unsigned short us8;

#define M_DIM 2048
#define N_DIM 32000
#define K_DIM 4096
#define BM 256
#define BN 256
#define BK 64
#define NT (K_DIM / BK)       // 64 K-tiles
#define MBLKS (M_DIM / BM)    // 8
#define NBLKS (N_DIM / BN)    // 125
#define NWG (MBLKS * NBLKS)   // 1000, divisible by 8

#define W_ELEMS ((size_t)N_DIM * K_DIM)
#define H_ELEMS ((size_t)M_DIM * K_DIM)
#define WS_NEEDED ((W_ELEMS + H_ELEMS) * 2)

#define GLOAD_LDS16(g, l) \
    __builtin_amdgcn_global_load_lds( \
        (const __attribute__((address_space(1))) unsigned int*)(g), \
        (__attribute__((address_space(3))) unsigned int*)(l), 16, 0, 0)

__device__ __forceinline__ unsigned short f2bf_rn(float f) {
    unsigned int u = __float_as_uint(f);
    u += 0x7FFFu + ((u >> 16) & 1u);
    return (unsigned short)(u >> 16);
}

// ---------------- fp32 -> bf16 conversion pass (memory-bound) ----------------
__global__ __launch_bounds__(256)
void cvt_f32_bf16(const float* __restrict__ in, unsigned short* __restrict__ out,
                  size_t n8) {
    size_t i = (size_t)blockIdx.x * blockDim.x + threadIdx.x;
    const size_t stride = (size_t)gridDim.x * blockDim.x;
    for (; i < n8; i += stride) {
        const float4 v0 = ((const float4*)in)[i * 2];
        const float4 v1 = ((const float4*)in)[i * 2 + 1];
        us8 p;
        p[0] = f2bf_rn(v0.x); p[1] = f2bf_rn(v0.y);
        p[2] = f2bf_rn(v0.z); p[3] = f2bf_rn(v0.w);
        p[4] = f2bf_rn(v1.x); p[5] = f2bf_rn(v1.y);
        p[6] = f2bf_rn(v1.z); p[7] = f2bf_rn(v1.w);
        ((us8*)out)[i] = p;
    }
}

// ---------------- 256^2 pipelined bf16 GEMM ----------------
// LDS (elems): A half (b,h) at (b*2+h)*8192 ; B half at 32768 + (b*2+h)*8192.
// lds[row][g] holds global granule g ^ (row&7) (granule = 8 bf16 = 16 B).
// Per K-tile t (buf B = t&1):
//  h0: issue SB<-(t,kk1) [12 ds_read]; lgkmcnt(12); 32 MFMA on SA(t,kk0)
//  h1: vmcnt(0)+lgkmcnt(0); s_barrier; stage(t+2)->buf B [8 gload_lds];
//      issue SA<-(t+1,kk0) from buf B^1 [12 ds_read]; 32 MFMA on SB(t,kk1)
__global__ __launch_bounds__(512, 2)
void lmhead_gemm_256(const unsigned short* __restrict__ A,  // [2048][4096] bf16
                     const unsigned short* __restrict__ W,  // [32000][4096] bf16
                     const float* __restrict__ bias,
                     float* __restrict__ C)
{
    __shared__ unsigned short lds[65536];  // 128 KB

    const int tid  = threadIdx.x;
    const int bid  = blockIdx.x;
    const int wgid = (bid & 7) * (NWG / 8) + (bid >> 3);  // bijective XCD chunks
    const int mblk = wgid & (MBLKS - 1);                  // M fastest-varying
    const int nblk = wgid >> 3;

    const int lane = tid & 63;
    const int wv   = tid >> 6;     // 0..7
    const int wr   = wv >> 2;      // 0..1 : wave M-half (128 rows)
    const int wc   = wv & 3;       // 0..3 : wave N-slot (64 cols)
    const int l15  = lane & 15;
    const int l4   = lane >> 4;

    // ---- staging addressing ----
    const int strow = tid >> 3;                          // 0..63
    const int sgsw  = ((tid & 7) ^ (strow & 7)) << 3;    // pre-swizzled k-off
    const unsigned short* const srcA = A + (size_t)(mblk * BM + strow) * K_DIM + sgsw;
    const unsigned short* const srcB = W + (size_t)(nblk * BN + strow) * K_DIM + sgsw;
    const int dstw = (tid & 448) * 8;                    // wave-uniform LDS base

#define STAGE_A(u, h, BUF) { \
        const unsigned short* s_ = srcA + (size_t)((h) * 128) * K_DIM + (size_t)(u) * BK; \
        unsigned short* d_ = &lds[(((BUF) * 2 + (h)) * 8192) + dstw]; \
        GLOAD_LDS16(s_, d_); GLOAD_LDS16(s_ + (size_t)64 * K_DIM, d_ + 4096); }
#define STAGE_B(u, h, BUF) { \
        const unsigned short* s_ = srcB + (size_t)((h) * 128) * K_DIM + (size_t)(u) * BK; \
        unsigned short* d_ = &lds[32768 + (((BUF) * 2 + (h)) * 8192) + dstw]; \
        GLOAD_LDS16(s_, d_); GLOAD_LDS16(s_ + (size_t)64 * K_DIM, d_ + 4096); }
#define STAGE_TILE(u, BUF) { \
        STAGE_A(u, 0, BUF); STAGE_A(u, 1, BUF); \
        STAGE_B(u, 0, BUF); STAGE_B(u, 1, BUF); }

    // ---- fragment read addressing ----
    const int swz0 = (l4 ^ (l15 & 7)) << 3;          // kk=0 swizzled granule
    const int swz1 = ((4 + l4) ^ (l15 & 7)) << 3;    // kk=1
    const int arow = l15 * 64;
    const int brow = ((wc & 1) * 64 + l15) * 64;

    const unsigned short* const asp[2] = { &lds[wr * 8192],
                                           &lds[(2 + wr) * 8192] };
    const unsigned short* const bsp[2] = { &lds[32768 + (wc >> 1) * 8192],
                                           &lds[32768 + (2 + (wc >> 1)) * 8192] };

    f32x4 acc[8][4] = {};
    bhalf8 aA[8], bA[4];   // set SA (kk=0 of current tile)
    bhalf8 aB[8], bB[4];   // set SB (kk=1 of current tile)

#define ISSUE_FRAGS(av, bv, as_, bs_, swz) { \
        const unsigned short* _as = (as_); const unsigned short* _bs = (bs_); \
        _Pragma("unroll") \
        for (int i = 0; i < 4; ++i) av[i]     = *(const bhalf8*)&_as[arow + (swz) + i * 1024]; \
        _Pragma("unroll") \
        for (int i = 0; i < 4; ++i) av[4 + i] = *(const bhalf8*)&_as[arow + (swz) + 4096 + i * 1024]; \
        _Pragma("unroll") \
        for (int j = 0; j < 4; ++j) bv[j]     = *(const bhalf8*)&_bs[brow + (swz) + j * 1024]; }

#define MFMA32(av, bv) { \
        _Pragma("unroll") \
        for (int i = 0; i < 8; ++i) \
            _Pragma("unroll") \
            for (int j = 0; j < 4; ++j) \
                acc[i][j] = __builtin_amdgcn_mfma_f32_16x16x32_bf16(av[i], bv[j], acc[i][j], 0, 0, 0); }

    // ---- prologue: stage tiles 0,1; tile0 landed everywhere; SA <- (0,kk0) ----
    STAGE_TILE(0, 0);
    STAGE_TILE(1, 1);
    asm volatile("s_waitcnt vmcnt(8)" ::: "memory");
    __builtin_amdgcn_sched_barrier(0);
    __builtin_amdgcn_s_barrier();
    ISSUE_FRAGS(aA, bA, asp[0], bsp[0], swz0);

#define TILE_STEP(T, B) { \
        /* h0 */ \
        ISSUE_FRAGS(aB, bB, asp[B], bsp[B], swz1); \
        __builtin_amdgcn_sched_barrier(0); \
        asm volatile("s_waitcnt lgkmcnt(12)" ::: "memory"); \
        __builtin_amdgcn_sched_barrier(0); \
        __builtin_amdgcn_s_setprio(1); \
        MFMA32(aA, bA); \
        __builtin_amdgcn_s_setprio(0); \
        /* h1 */ \
        asm volatile("s_waitcnt vmcnt(0) lgkmcnt(0)" ::: "memory"); \
        __builtin_amdgcn_sched_barrier(0); \
        __builtin_amdgcn_s_barrier(); \
        if ((T) + 2 < NT) STAGE_TILE((T) + 2, B); \
        if ((T) + 1 < NT) ISSUE_FRAGS(aA, bA, asp[B ^ 1], bsp[B ^ 1], swz0); \
        __builtin_amdgcn_sched_barrier(0); \
        __builtin_amdgcn_s_setprio(1); \
        MFMA32(aB, bB); \
        __builtin_amdgcn_s_setprio(0); }

    #pragma unroll 1
    for (int t = 0; t < NT; t += 2) {
        TILE_STEP(t, 0);
        TILE_STEP(t + 1, 1);
    }

    // ---- epilogue: D map row=(lane>>4)*4+r, col=lane&15; nontemporal C ----
    const size_t crow0 = (size_t)(mblk * BM + wr * 128 + l4 * 4);
    const int    ccol0 = nblk * BN + wc * 64 + l15;
    #pragma unroll
    for (int j = 0; j < 4; ++j) {
        const float bv = bias[ccol0 + j * 16];
        #pragma unroll
        for (int i = 0; i < 8; ++i) {
            const size_t base = (crow0 + (size_t)i * 16) * N_DIM + ccol0 + j * 16;
            #pragma unroll
            for (int r = 0; r < 4; ++r)
                __builtin_nontemporal_store(acc[i][j][r] + bv,
                                            &C[base + (size_t)r * N_DIM]);
        }
    }
#undef STAGE_A
#undef STAGE_B
#undef STAGE_TILE
#undef ISSUE_FRAGS
#undef MFMA32
#undef TILE_STEP
}

// ---------------- fallback (fp32 inputs, reg-staged 128^2) ----------------
__global__ __launch_bounds__(256, 2)
void lmhead_gemm_f32(const float* __restrict__ A, const float* __restrict__ W,
                     const float* __restrict__ bias, float* __restrict__ C) {
    __shared__ unsigned short As[2][128 * 64];
    __shared__ unsigned short Bs[2][128 * 64];

    const int tid  = threadIdx.x;
    const int bid  = blockIdx.x;
    const int mblk = bid & 15;
    const int nblk = bid >> 4;
    const int st_row = tid >> 3;
    const int st_g   = tid & 7;
    const int lane = tid & 63;
    const int wv   = tid >> 6;
    const int wm   = (wv >> 1) << 6;
    const int wn   = (wv & 1) << 6;
    const int l15  = lane & 15;
    const int l4   = lane >> 4;

    const float* aptr = A + (size_t)(mblk * 128 + st_row) * K_DIM + st_g * 8;
    const float* bptr = W + (size_t)(nblk * 128 + st_row) * K_DIM + st_g * 8;

    f32x4 acc[4][4] = {};
    float4 ra[4][2], rb[4][2];

    #pragma unroll
    for (int s = 0; s < 4; ++s) {
        const float* ap = aptr + (size_t)(s * 32) * K_DIM;
        const float* bp = bptr + (size_t)(s * 32) * K_DIM;
        ra[s][0] = *(const float4*)(ap);   ra[s][1] = *(const float4*)(ap + 4);
        rb[s][0] = *(const float4*)(bp);   rb[s][1] = *(const float4*)(bp + 4);
    }
    #pragma unroll
    for (int s = 0; s < 4; ++s) {
        const int row = s * 32 + st_row;
        const int off = row * 64 + ((st_g ^ (row & 7)) << 3);
        us8 pa, pb;
        #pragma unroll
        for (int j = 0; j < 4; ++j) {
            pa[j] = f2bf_rn(((const float*)&ra[s][0])[j]);
            pa[j + 4] = f2bf_rn(((const float*)&ra[s][1])[j]);
            pb[j] = f2bf_rn(((const float*)&rb[s][0])[j]);
            pb[j + 4] = f2bf_rn(((const float*)&rb[s][1])[j]);
        }
        *(us8*)&As[0][off] = pa;  *(us8*)&Bs[0][off] = pb;
    }
    __syncthreads();

    for (int t = 0; t < 64; ++t) {
        const int cur = t & 1;
        const bool more = (t + 1) < 64;
        if (more) {
            const float* ap = aptr + (size_t)(t + 1) * 64;
            const float* bp = bptr + (size_t)(t + 1) * 64;
            #pragma unroll
            for (int s = 0; s < 4; ++s) {
                ra[s][0] = *(const float4*)(ap + (size_t)(s * 32) * K_DIM);
                ra[s][1] = *(const float4*)(ap + (size_t)(s * 32) * K_DIM + 4);
                rb[s][0] = *(const float4*)(bp + (size_t)(s * 32) * K_DIM);
                rb[s][1] = *(const float4*)(bp + (size_t)(s * 32) * K_DIM + 4);
            }
        }
        const unsigned short* as = As[cur];
        const unsigned short* bs = Bs[cur];
        #pragma unroll
        for (int kk = 0; kk < 2; ++kk) {
            bhalf8 af[4], bfv[4];
            #pragma unroll
            for (int mf = 0; mf < 4; ++mf) {
                const int row = wm + mf * 16 + l15;
                af[mf] = *(const bhalf8*)&as[row * 64 + ((((kk << 2) + l4) ^ (row & 7)) << 3)];
            }
            #pragma unroll
            for (int nf = 0; nf < 4; ++nf) {
                const int row = wn + nf * 16 + l15;
                bfv[nf] = *(const bhalf8*)&bs[row * 64 + ((((kk << 2) + l4) ^ (row & 7)) << 3)];
            }
            #pragma unroll
            for (int mf = 0; mf < 4; ++mf)
                #pragma unroll
                for (int nf = 0; nf < 4; ++nf)
                    acc[mf][nf] = __builtin_amdgcn_mfma_f32_16x16x32_bf16(
                        af[mf], bfv[nf], acc[mf][nf], 0, 0, 0);
        }
        if (more) {
            const int nbuf = cur ^ 1;
            #pragma unroll
            for (int s = 0; s < 4; ++s) {
                const int row = s * 32 + st_row;
                const int off = row * 64 + ((st_g ^ (row & 7)) << 3);
                us8 pa, pb;
                #pragma unroll
                for (int j = 0; j < 4; ++j) {
                    pa[j] = f2bf_rn(((const float*)&ra[s][0])[j]);
                    pa[j + 4] = f2bf_rn(((const float*)&ra[s][1])[j]);
                    pb[j] = f2bf_rn(((const float*)&rb[s][0])[j]);
                    pb[j + 4] = f2bf_rn(((const float*)&rb[s][1])[j]);
                }
                *(us8*)&As[nbuf][off] = pa;  *(us8*)&Bs[nbuf][off] = pb;
            }
        }
        __syncthreads();
    }

    const size_t crow0 = (size_t)(mblk * 128 + wm + l4 * 4);
    const int    ccol0 = nblk * 128 + wn + l15;
    #pragma unroll
    for (int nf = 0; nf < 4; ++nf) {
        const float bv = bias[ccol0 + nf * 16];
        #pragma unroll
        for (int mf = 0; mf < 4; ++mf) {
            const size_t base = (crow0 + (size_t)mf * 16) * N_DIM + ccol0 + nf * 16;
            #pragma unroll
            for (int r = 0; r < 4; ++r)
                C[base + (size_t)r * N_DIM] = acc[mf][nf][r] + bv;
        }
    }
}

extern "C" void kernel_launch(void* const* d_in, const int* in_sizes, int n_in,
                              void* d_out, int out_size, void* d_ws, size_t ws_size,
                              hipStream_t stream) {
    const float* h = (const float*)d_in[0];
    const float* w = (const float*)d_in[1];
    const float* b = (const float*)d_in[2];
    float* out = (float*)d_out;
    // split_num (d_in[3]) is a semantic no-op: K-slices sum to the full GEMM.

    if (ws_size >= WS_NEEDED) {
        unsigned short* wbf = (unsigned short*)d_ws;
        unsigned short* hbf = wbf + W_ELEMS;
        cvt_f32_bf16<<<2048, 256, 0, stream>>>(w, wbf, W_ELEMS / 8);
        cvt_f32_bf16<<<512, 256, 0, stream>>>(h, hbf, H_ELEMS / 8);
        lmhead_gemm_256<<<NWG, 512, 0, stream>>>(hbf, wbf, b, out);
    } else {
        lmhead_gemm_f32<<<4000, 256, 0, stream>>>(h, w, b, out);
    }
}

// Round 5
// 620.741 us; speedup vs baseline: 3.2191x; 3.2191x over previous
//
#include <hip/hip_runtime.h>
#include <hip/hip_bf16.h>

// SlicedLMHead: logits[2048][32000] = H[2048][4096] @ W[32000][4096]^T + bias
// Round 5: cvt W,H -> bf16 in d_ws, then 256x256 GEMM, 4 phases/K-tile with
// reads issued 1-2 phases early under MFMA (counted lgkmcnt), counted vmcnt(4)
// (never 0 mid-loop), 1 barrier/phase, plain C stores (nt stores were a 10x
// HBM-write disaster in round 4).

typedef __attribute__((ext_vector_type(8))) short bhalf8;   // 8 bf16
typedef __attribute__((ext_vector_type(4))) float f32x4;    // MFMA acc
typedef __attribute__((ext_vector_type(8))) unsigned short us8;

#define M_DIM 2048
#define N_DIM 32000
#define K_DIM 4096
#define BM 256
#define BN 256
#define BK 64
#define NT (K_DIM / BK)       // 64 K-tiles
#define MBLKS (M_DIM / BM)    // 8
#define NBLKS (N_DIM / BN)    // 125
#define NWG (MBLKS * NBLKS)   // 1000, divisible by 8

#define W_ELEMS ((size_t)N_DIM * K_DIM)
#define H_ELEMS ((size_t)M_DIM * K_DIM)
#define WS_NEEDED ((W_ELEMS + H_ELEMS) * 2)

#define GLOAD_LDS16(g, l) \
    __builtin_amdgcn_global_load_lds( \
        (const __attribute__((address_space(1))) unsigned int*)(g), \
        (__attribute__((address_space(3))) unsigned int*)(l), 16, 0, 0)

__device__ __forceinline__ unsigned short f2bf_rn(float f) {
    unsigned int u = __float_as_uint(f);
    u += 0x7FFFu + ((u >> 16) & 1u);
    return (unsigned short)(u >> 16);
}

// ---------------- fp32 -> bf16 conversion pass (memory-bound) ----------------
__global__ __launch_bounds__(256)
void cvt_f32_bf16(const float* __restrict__ in, unsigned short* __restrict__ out,
                  size_t n8) {
    size_t i = (size_t)blockIdx.x * blockDim.x + threadIdx.x;
    const size_t stride = (size_t)gridDim.x * blockDim.x;
    for (; i < n8; i += stride) {
        const float4 v0 = ((const float4*)in)[i * 2];
        const float4 v1 = ((const float4*)in)[i * 2 + 1];
        us8 p;
        p[0] = f2bf_rn(v0.x); p[1] = f2bf_rn(v0.y);
        p[2] = f2bf_rn(v0.z); p[3] = f2bf_rn(v0.w);
        p[4] = f2bf_rn(v1.x); p[5] = f2bf_rn(v1.y);
        p[6] = f2bf_rn(v1.z); p[7] = f2bf_rn(v1.w);
        ((us8*)out)[i] = p;
    }
}

// ---------------- 256^2 bf16 GEMM, read-under-MFMA schedule ----------------
// LDS (elems): A half (buf,h) at (buf*2+h)*8192; B half at 32768+(buf*2+h)*8192.
// lds[row][g] holds global granule g ^ (row&7) (granule = 8 bf16 = 16 B).
// Quadrants: ph0 q00(af0*bf01) ph1 q01(af0*bf23) ph2 q10(af1*bf01) ph3 q11(af1*bf23)
// Reads:  ph0: bf01,bf23 (8)   ph1: af1 (8)   ph3 (post-vmcnt): af0' next tile (8)
// Stages: ph0: B(t+1,0)  ph1: B(t+1,1)  ph3: A(t+2,0)+A(t+2,1); vmcnt(4) at ph3.
__global__ __launch_bounds__(512, 2)
void lmhead_gemm_256(const unsigned short* __restrict__ A,  // [2048][4096] bf16
                     const unsigned short* __restrict__ W,  // [32000][4096] bf16
                     const float* __restrict__ bias,
                     float* __restrict__ C)
{
    __shared__ unsigned short lds[65536];  // 128 KB

    const int tid  = threadIdx.x;
    const int bid  = blockIdx.x;
    const int wgid = (bid & 7) * (NWG / 8) + (bid >> 3);  // bijective XCD chunks
    const int mblk = wgid & (MBLKS - 1);                  // M fastest-varying
    const int nblk = wgid >> 3;

    const int lane = tid & 63;
    const int wv   = tid >> 6;     // 0..7
    const int wr   = wv >> 2;      // 0..1 : wave M-half (128 rows)
    const int wc   = wv & 3;       // 0..3 : wave N-slot (64 cols)
    const int l15  = lane & 15;
    const int l4   = lane >> 4;

    // ---- staging addressing ----
    const int strow = tid >> 3;                          // 0..63
    const int sgsw  = ((tid & 7) ^ (strow & 7)) << 3;    // pre-swizzled k-off
    const unsigned short* const srcA = A + (size_t)(mblk * BM + strow) * K_DIM + sgsw;
    const unsigned short* const srcB = W + (size_t)(nblk * BN + strow) * K_DIM + sgsw;
    const int dstw = (tid & 448) * 8;                    // wave-uniform LDS base

#define STAGE_A(u, h, BUF) { \
        const unsigned short* s_ = srcA + (size_t)((h) * 128) * K_DIM + (size_t)(u) * BK; \
        unsigned short* d_ = &lds[(((BUF) * 2 + (h)) * 8192) + dstw]; \
        GLOAD_LDS16(s_, d_); GLOAD_LDS16(s_ + (size_t)64 * K_DIM, d_ + 4096); }
#define STAGE_B(u, h, BUF) { \
        const unsigned short* s_ = srcB + (size_t)((h) * 128) * K_DIM + (size_t)(u) * BK; \
        unsigned short* d_ = &lds[32768 + (((BUF) * 2 + (h)) * 8192) + dstw]; \
        GLOAD_LDS16(s_, d_); GLOAD_LDS16(s_ + (size_t)64 * K_DIM, d_ + 4096); }

    // ---- fragment read addressing ----
    const int swz0 = (l4 ^ (l15 & 7)) << 3;          // kk=0 swizzled granule
    const int swz1 = ((4 + l4) ^ (l15 & 7)) << 3;    // kk=1
    const int aoff0 = l15 * 64 + swz0;
    const int aoff1 = l15 * 64 + swz1;
    const int boff0 = ((wc & 1) * 64 + l15) * 64 + swz0;
    const int boff1 = ((wc & 1) * 64 + l15) * 64 + swz1;

    f32x4 acc[8][4] = {};
    bhalf8 af0[4][2], af1[4][2], bf01[2][2], bf23[2][2];

    // ---- prologue: stage A(0),B(0) -> buf0, A(1) -> buf1; read af0(tile0) ----
    STAGE_A(0, 0, 0); STAGE_A(0, 1, 0);
    STAGE_B(0, 0, 0); STAGE_B(0, 1, 0);
    STAGE_A(1, 0, 1); STAGE_A(1, 1, 1);
    asm volatile("s_waitcnt vmcnt(4)" ::: "memory");   // tile0 landed; A(1) flying
    __builtin_amdgcn_sched_barrier(0);
    __builtin_amdgcn_s_barrier();
    {
        const unsigned short* a0 = &lds[wr * 8192];
        #pragma unroll
        for (int i = 0; i < 4; ++i) {
            af0[i][0] = *(const bhalf8*)&a0[aoff0 + i * 1024];
            af0[i][1] = *(const bhalf8*)&a0[aoff1 + i * 1024];
        }
    }

    #pragma unroll 1
    for (int t = 0; t < NT; ++t) {
        const int b = t & 1;
        const unsigned short* asb = &lds[(b * 2 + wr) * 8192];
        const unsigned short* bsb = &lds[32768 + (b * 2 + (wc >> 1)) * 8192];
        const unsigned short* asn = &lds[((b ^ 1) * 2 + wr) * 8192];

        // ===== ph0: read bf01+bf23 (8); stage B(t+1,0); wait af0'+bf01; q00 =====
        #pragma unroll
        for (int j = 0; j < 2; ++j) {
            bf01[j][0] = *(const bhalf8*)&bsb[boff0 + j * 1024];
            bf01[j][1] = *(const bhalf8*)&bsb[boff1 + j * 1024];
        }
        #pragma unroll
        for (int j = 0; j < 2; ++j) {
            bf23[j][0] = *(const bhalf8*)&bsb[boff0 + (2 + j) * 1024];
            bf23[j][1] = *(const bhalf8*)&bsb[boff1 + (2 + j) * 1024];
        }
        if (t + 1 < NT) STAGE_B(t + 1, 0, b ^ 1);
        __builtin_amdgcn_sched_barrier(0);
        asm volatile("s_waitcnt lgkmcnt(4)" ::: "memory");  // af0 + bf01 landed
        __builtin_amdgcn_sched_barrier(0);
        __builtin_amdgcn_s_setprio(1);
        #pragma unroll
        for (int i = 0; i < 4; ++i)
            #pragma unroll
            for (int j = 0; j < 2; ++j)
                #pragma unroll
                for (int kk = 0; kk < 2; ++kk)
                    acc[i][j] = __builtin_amdgcn_mfma_f32_16x16x32_bf16(
                        af0[i][kk], bf01[j][kk], acc[i][j], 0, 0, 0);
        __builtin_amdgcn_s_setprio(0);
        __builtin_amdgcn_s_barrier();

        // ===== ph1: read af1 (8); stage B(t+1,1); wait bf23; q01 =====
        #pragma unroll
        for (int i = 0; i < 4; ++i) {
            af1[i][0] = *(const bhalf8*)&asb[aoff0 + 4096 + i * 1024];
            af1[i][1] = *(const bhalf8*)&asb[aoff1 + 4096 + i * 1024];
        }
        if (t + 1 < NT) STAGE_B(t + 1, 1, b ^ 1);
        __builtin_amdgcn_sched_barrier(0);
        asm volatile("s_waitcnt lgkmcnt(8)" ::: "memory");  // bf23 landed
        __builtin_amdgcn_sched_barrier(0);
        __builtin_amdgcn_s_setprio(1);
        #pragma unroll
        for (int i = 0; i < 4; ++i)
            #pragma unroll
            for (int j = 0; j < 2; ++j)
                #pragma unroll
                for (int kk = 0; kk < 2; ++kk)
                    acc[i][2 + j] = __builtin_amdgcn_mfma_f32_16x16x32_bf16(
                        af0[i][kk], bf23[j][kk], acc[i][2 + j], 0, 0, 0);
        __builtin_amdgcn_s_setprio(0);
        __builtin_amdgcn_s_barrier();

        // ===== ph2: wait af1; q10 =====
        asm volatile("s_waitcnt lgkmcnt(0)" ::: "memory");  // af1 landed
        __builtin_amdgcn_sched_barrier(0);
        __builtin_amdgcn_s_setprio(1);
        #pragma unroll
        for (int i = 0; i < 4; ++i)
            #pragma unroll
            for (int j = 0; j < 2; ++j)
                #pragma unroll
                for (int kk = 0; kk < 2; ++kk)
                    acc[4 + i][j] = __builtin_amdgcn_mfma_f32_16x16x32_bf16(
                        af1[i][kk], bf01[j][kk], acc[4 + i][j], 0, 0, 0);
        __builtin_amdgcn_s_setprio(0);
        __builtin_amdgcn_s_barrier();

        // ===== ph3: stage A(t+2); q11; vmcnt(4); read af0'(t+1) post-drain =====
        if (t + 2 < NT) { STAGE_A(t + 2, 0, b); STAGE_A(t + 2, 1, b); }
        __builtin_amdgcn_sched_barrier(0);
        __builtin_amdgcn_s_setprio(1);
        #pragma unroll
        for (int i = 0; i < 4; ++i)
            #pragma unroll
            for (int j = 0; j < 2; ++j)
                #pragma unroll
                for (int kk = 0; kk < 2; ++kk)
                    acc[4 + i][2 + j] = __builtin_amdgcn_mfma_f32_16x16x32_bf16(
                        af1[i][kk], bf23[j][kk], acc[4 + i][2 + j], 0, 0, 0);
        __builtin_amdgcn_s_setprio(0);
        __builtin_amdgcn_sched_barrier(0);
        if (t < NT - 2) { asm volatile("s_waitcnt vmcnt(4)" ::: "memory"); }
        else            { asm volatile("s_waitcnt vmcnt(0)" ::: "memory"); }
        __builtin_amdgcn_sched_barrier(0);
        if (t + 1 < NT) {   // A(t+1) just drained; read next tile's af0
            #pragma unroll
            for (int i = 0; i < 4; ++i) {
                af0[i][0] = *(const bhalf8*)&asn[aoff0 + i * 1024];
                af0[i][1] = *(const bhalf8*)&asn[aoff1 + i * 1024];
            }
        }
        __builtin_amdgcn_sched_barrier(0);
        __builtin_amdgcn_s_barrier();
    }

    // ---- epilogue: D map row=(lane>>4)*4+r, col=lane&15 ----
    const size_t crow0 = (size_t)(mblk * BM + wr * 128 + l4 * 4);
    const int    ccol0 = nblk * BN + wc * 64 + l15;
    #pragma unroll
    for (int j = 0; j < 4; ++j) {
        const float bv = bias[ccol0 + j * 16];
        #pragma unroll
        for (int i = 0; i < 8; ++i) {
            const size_t base = (crow0 + (size_t)i * 16) * N_DIM + ccol0 + j * 16;
            #pragma unroll
            for (int r = 0; r < 4; ++r)
                C[base + (size_t)r * N_DIM] = acc[i][j][r] + bv;
        }
    }
#undef STAGE_A
#undef STAGE_B
}

// ---------------- fallback (fp32 inputs, reg-staged 128^2) ----------------
__global__ __launch_bounds__(256, 2)
void lmhead_gemm_f32(const float* __restrict__ A, const float* __restrict__ W,
                     const float* __restrict__ bias, float* __restrict__ C) {
    __shared__ unsigned short As[2][128 * 64];
    __shared__ unsigned short Bs[2][128 * 64];

    const int tid  = threadIdx.x;
    const int bid  = blockIdx.x;
    const int mblk = bid & 15;
    const int nblk = bid >> 4;
    const int st_row = tid >> 3;
    const int st_g   = tid & 7;
    const int lane = tid & 63;
    const int wv   = tid >> 6;
    const int wm   = (wv >> 1) << 6;
    const int wn   = (wv & 1) << 6;
    const int l15  = lane & 15;
    const int l4   = lane >> 4;

    const float* aptr = A + (size_t)(mblk * 128 + st_row) * K_DIM + st_g * 8;
    const float* bptr = W + (size_t)(nblk * 128 + st_row) * K_DIM + st_g * 8;

    f32x4 acc[4][4] = {};
    float4 ra[4][2], rb[4][2];

    #pragma unroll
    for (int s = 0; s < 4; ++s) {
        const float* ap = aptr + (size_t)(s * 32) * K_DIM;
        const float* bp = bptr + (size_t)(s * 32) * K_DIM;
        ra[s][0] = *(const float4*)(ap);   ra[s][1] = *(const float4*)(ap + 4);
        rb[s][0] = *(const float4*)(bp);   rb[s][1] = *(const float4*)(bp + 4);
    }
    #pragma unroll
    for (int s = 0; s < 4; ++s) {
        const int row = s * 32 + st_row;
        const int off = row * 64 + ((st_g ^ (row & 7)) << 3);
        us8 pa, pb;
        #pragma unroll
        for (int j = 0; j < 4; ++j) {
            pa[j] = f2bf_rn(((const float*)&ra[s][0])[j]);
            pa[j + 4] = f2bf_rn(((const float*)&ra[s][1])[j]);
            pb[j] = f2bf_rn(((const float*)&rb[s][0])[j]);
            pb[j + 4] = f2bf_rn(((const float*)&rb[s][1])[j]);
        }
        *(us8*)&As[0][off] = pa;  *(us8*)&Bs[0][off] = pb;
    }
    __syncthreads();

    for (int t = 0; t < 64; ++t) {
        const int cur = t & 1;
        const bool more = (t + 1) < 64;
        if (more) {
            const float* ap = aptr + (size_t)(t + 1) * 64;
            const float* bp = bptr + (size_t)(t + 1) * 64;
            #pragma unroll
            for (int s = 0; s < 4; ++s) {
                ra[s][0] = *(const float4*)(ap + (size_t)(s * 32) * K_DIM);
                ra[s][1] = *(const float4*)(ap + (size_t)(s * 32) * K_DIM + 4);
                rb[s][0] = *(const float4*)(bp + (size_t)(s * 32) * K_DIM);
                rb[s][1] = *(const float4*)(bp + (size_t)(s * 32) * K_DIM + 4);
            }
        }
        const unsigned short* as = As[cur];
        const unsigned short* bs = Bs[cur];
        #pragma unroll
        for (int kk = 0; kk < 2; ++kk) {
            bhalf8 af[4], bfv[4];
            #pragma unroll
            for (int mf = 0; mf < 4; ++mf) {
                const int row = wm + mf * 16 + l15;
                af[mf] = *(const bhalf8*)&as[row * 64 + ((((kk << 2) + l4) ^ (row & 7)) << 3)];
            }
            #pragma unroll
            for (int nf = 0; nf < 4; ++nf) {
                const int row = wn + nf * 16 + l15;
                bfv[nf] = *(const bhalf8*)&bs[row * 64 + ((((kk << 2) + l4) ^ (row & 7)) << 3)];
            }
            #pragma unroll
            for (int mf = 0; mf < 4; ++mf)
                #pragma unroll
                for (int nf = 0; nf < 4; ++nf)
                    acc[mf][nf] = __builtin_amdgcn_mfma_f32_16x16x32_bf16(
                        af[mf], bfv[nf], acc[mf][nf], 0, 0, 0);
        }
        if (more) {
            const int nbuf = cur ^ 1;
            #pragma unroll
            for (int s = 0; s < 4; ++s) {
                const int row = s * 32 + st_row;
                const int off = row * 64 + ((st_g ^ (row & 7)) << 3);
                us8 pa, pb;
                #pragma unroll
                for (int j = 0; j < 4; ++j) {
                    pa[j] = f2bf_rn(((const float*)&ra[s][0])[j]);
                    pa[j + 4] = f2bf_rn(((const float*)&ra[s][1])[j]);
                    pb[j] = f2bf_rn(((const float*)&rb[s][0])[j]);
                    pb[j + 4] = f2bf_rn(((const float*)&rb[s][1])[j]);
                }
                *(us8*)&As[nbuf][off] = pa;  *(us8*)&Bs[nbuf][off] = pb;
            }
        }
        __syncthreads();
    }

    const size_t crow0 = (size_t)(mblk * 128 + wm + l4 * 4);
    const int    ccol0 = nblk * 128 + wn + l15;
    #pragma unroll
    for (int nf = 0; nf < 4; ++nf) {
        const float bv = bias[ccol0 + nf * 16];
        #pragma unroll
        for (int mf = 0; mf < 4; ++mf) {
            const size_t base = (crow0 + (size_t)mf * 16) * N_DIM + ccol0 + nf * 16;
            #pragma unroll
            for (int r = 0; r < 4; ++r)
                C[base + (size_t)r * N_DIM] = acc[mf][nf][r] + bv;
        }
    }
}

extern "C" void kernel_launch(void* const* d_in, const int* in_sizes, int n_in,
                              void* d_out, int out_size, void* d_ws, size_t ws_size,
                              hipStream_t stream) {
    const float* h = (const float*)d_in[0];
    const float* w = (const float*)d_in[1];
    const float* b = (const float*)d_in[2];
    float* out = (float*)d_out;
    // split_num (d_in[3]) is a semantic no-op: K-slices sum to the full GEMM.

    if (ws_size >= WS_NEEDED) {
        unsigned short* wbf = (unsigned short*)d_ws;
        unsigned short* hbf = wbf + W_ELEMS;
        cvt_f32_bf16<<<2048, 256, 0, stream>>>(w, wbf, W_ELEMS / 8);
        cvt_f32_bf16<<<512, 256, 0, stream>>>(h, hbf, H_ELEMS / 8);
        lmhead_gemm_256<<<NWG, 512, 0, stream>>>(hbf, wbf, b, out);
    } else {
        lmhead_gemm_f32<<<4000, 256, 0, stream>>>(h, w, b, out);
    }
}